// Round 10
// baseline (683.796 us; speedup 1.0000x reference)
//
#include <hip/hip_runtime.h>
#include <float.h>

// Problem constants (from reference file)
constexpr int C    = 512;          // DIM_CODES
constexpr int K    = 512;          // DICT_SIZE
constexpr int E    = 16;           // EMBED_DIM
constexpr int B    = 512;          // BATCH
constexpr int MUS  = C * E;        // 8192, mu row stride
constexpr int R    = 2;            // query rows per lane (v10: was 4)

// native vector type for nontemporal 16B stores
typedef float f32x4 __attribute__((ext_vector_type(4)));

// ============================================================================
// Kernel 1 — argmin scan. v10 = v7 hot loop at the occupancy/LDS balance
// point identified by the v4/v5/v7/v9 scaling law:
//   - 1 wave/SIMD (v7):  latency-bound, 512 iters x ~1050 cyc = 224us
//   - 4 waves/SIMD (v4): LDS-pipe-bound, 16 w/CU x 512 x 5 instr x 12cyc=255us
// Coverage constraint waves/CU x R = 16  =>  R=2 @ 8 waves/CU (2/SIMD)
// balances both terms (~112us each, overlapped). Plus nrm packed as float4
// (one b128 per 4 k's => 4.25 LDS instr/iter instead of 5; same values,
// same fma order => bit-identical).
// Geometry: 256-thread blocks (4 waves), one block per c, lane row
// b = tid + 256*s. Tie logic / epilogue unchanged from verified v7.
// ============================================================================
__launch_bounds__(256, 2)
__global__ void vq_scan(const float* __restrict__ mu,
                        const float* __restrict__ dict,
                        float* __restrict__ z,
                        float* __restrict__ zq,
                        int*   __restrict__ idx_t)
{
    const int c    = blockIdx.x;
    const int tid  = threadIdx.x;
    const int lane = tid & 63;
    const int wave = tid >> 6;

    __shared__ __align__(16) float dict_s[K * E];   // 32 KB
    __shared__ __align__(16) float nrm_s[K];        // 2 KB (read as float4)

    const float* __restrict__ dbase = dict + (size_t)c * K * E;

    // ---- stage dict slice + per-code squared norms (verified fma order)
#pragma unroll
    for (int rep = 0; rep < 2; ++rep) {
        const int k = tid + rep * 256;
        const float4* p = reinterpret_cast<const float4*>(dbase + k * E);
        const float4 d0 = p[0], d1 = p[1], d2 = p[2], d3 = p[3];
        float s = d0.x * d0.x;
        s = fmaf(d0.y, d0.y, s); s = fmaf(d0.z, d0.z, s); s = fmaf(d0.w, d0.w, s);
        s = fmaf(d1.x, d1.x, s); s = fmaf(d1.y, d1.y, s);
        s = fmaf(d1.z, d1.z, s); s = fmaf(d1.w, d1.w, s);
        s = fmaf(d2.x, d2.x, s); s = fmaf(d2.y, d2.y, s);
        s = fmaf(d2.z, d2.z, s); s = fmaf(d2.w, d2.w, s);
        s = fmaf(d3.x, d3.x, s); s = fmaf(d3.y, d3.y, s);
        s = fmaf(d3.z, d3.z, s); s = fmaf(d3.w, d3.w, s);
        float4* q4 = reinterpret_cast<float4*>(&dict_s[k * E]);
        q4[0] = d0; q4[1] = d1; q4[2] = d2; q4[3] = d3;
        nrm_s[k] = s;
    }
    __syncthreads();

    // ---- this lane's R query rows: row = tid + 256*s  (covers B=512)
    float4 m[R][4];
    float  nm[R];
#pragma unroll
    for (int s = 0; s < R; ++s) {
        const int b = tid + 256 * s;
        const float4* p = reinterpret_cast<const float4*>(
            mu + (size_t)b * MUS + c * E);
        m[s][0] = p[0]; m[s][1] = p[1]; m[s][2] = p[2]; m[s][3] = p[3];
        float v = m[s][0].x * m[s][0].x;
        v = fmaf(m[s][0].y, m[s][0].y, v);
        v = fmaf(m[s][0].z, m[s][0].z, v);
        v = fmaf(m[s][0].w, m[s][0].w, v);
#pragma unroll
        for (int t = 1; t < 4; ++t) {
            v = fmaf(m[s][t].x, m[s][t].x, v);
            v = fmaf(m[s][t].y, m[s][t].y, v);
            v = fmaf(m[s][t].z, m[s][t].z, v);
            v = fmaf(m[s][t].w, m[s][t].w, v);
        }
        nm[s] = v;
    }

    // ---- serial scan over all K codes; one dict broadcast feeds R rows;
    // nrm read once per 4 k's as float4.
    float bd[R], sec[R];
    int   bk[R];
#pragma unroll
    for (int s = 0; s < R; ++s) { bd[s] = FLT_MAX; sec[s] = FLT_MAX; bk[s] = K; }

    const float4* __restrict__ ds4 = reinterpret_cast<const float4*>(dict_s);
    const float4* __restrict__ nr4 = reinterpret_cast<const float4*>(nrm_s);

    for (int g = 0; g < K / 4; ++g) {
        const float4 nrq = nr4[g];
        const float  nrs[4] = { nrq.x, nrq.y, nrq.z, nrq.w };
#pragma unroll
        for (int u = 0; u < 4; ++u) {
            const int k = g * 4 + u;
            const float4 d0 = ds4[k * 4 + 0];
            const float4 d1 = ds4[k * 4 + 1];
            const float4 d2 = ds4[k * 4 + 2];
            const float4 d3 = ds4[k * 4 + 3];
            const float  nr = nrs[u];
#pragma unroll
            for (int s = 0; s < R; ++s) {
                float acc = d0.x * m[s][0].x;
                acc = fmaf(d0.y, m[s][0].y, acc);
                acc = fmaf(d0.z, m[s][0].z, acc);
                acc = fmaf(d0.w, m[s][0].w, acc);
                acc = fmaf(d1.x, m[s][1].x, acc);
                acc = fmaf(d1.y, m[s][1].y, acc);
                acc = fmaf(d1.z, m[s][1].z, acc);
                acc = fmaf(d1.w, m[s][1].w, acc);
                acc = fmaf(d2.x, m[s][2].x, acc);
                acc = fmaf(d2.y, m[s][2].y, acc);
                acc = fmaf(d2.z, m[s][2].z, acc);
                acc = fmaf(d2.w, m[s][2].w, acc);
                acc = fmaf(d3.x, m[s][3].x, acc);
                acc = fmaf(d3.y, m[s][3].y, acc);
                acc = fmaf(d3.z, m[s][3].z, acc);
                acc = fmaf(d3.w, m[s][3].w, acc);
                // identical rounding to the verified kernel
                const float dist = fmaf(-2.0f, acc, nm[s] + nr);
                const bool  lt   = dist < bd[s];          // ascending k =>
                sec[s] = lt ? bd[s] : fminf(sec[s], dist);   // first-index ties
                bd[s]  = lt ? dist : bd[s];
                bk[s]  = lt ? k : bk[s];
            }
        }
    }

    // ---- rare near-tie path: wave-cooperative fp64 re-scan per flagged row.
#pragma unroll
    for (int s = 0; s < R; ++s) {
        unsigned long long trig = __ballot(sec[s] < bd[s] + 1e-3f);
        while (trig) {
            const int r = __ffsll(trig) - 1;
            trig &= trig - 1;
            const int row = (wave << 6) + r + 256 * s;
            const float* __restrict__ qrow = mu + (size_t)row * MUS + c * E;

            double nmuD = 0.0;
#pragma unroll
            for (int t = 0; t < E; ++t) {
                const double mt = (double)qrow[t];
                nmuD += mt * mt;
            }
            double bD = DBL_MAX;
            int    bK = K;
#pragma unroll
            for (int i = 0; i < 8; ++i) {
                const int kk = lane + 64 * i;
                const float* dk = &dict_s[kk * E];
                double nd = 0.0, dt = 0.0;
#pragma unroll
                for (int t = 0; t < 4; ++t) {
                    const double dx = dk[4 * t + 0], dy = dk[4 * t + 1];
                    const double dz = dk[4 * t + 2], dw = dk[4 * t + 3];
                    const double mx = qrow[4 * t + 0], my = qrow[4 * t + 1];
                    const double mz = qrow[4 * t + 2], mw = qrow[4 * t + 3];
                    nd += dx * dx + dy * dy + dz * dz + dw * dw;
                    dt += dx * mx + dy * my + dz * mz + dw * mw;
                }
                const double dist = nmuD + nd - 2.0 * dt;
                if (dist < bD) { bD = dist; bK = kk; }
            }
#pragma unroll
            for (int off = 32; off; off >>= 1) {
                const double od = __shfl_down(bD, off);
                const int    ok = __shfl_down(bK, off);
                if (od < bD || (od == bD && ok < bK)) { bD = od; bK = ok; }
            }
            const int kwin = __shfl(bK, 0);
            if (lane == r) bk[s] = kwin;
        }
    }

    // ---- outputs per slot: idx (coalesced), z/zq from registers.
#pragma unroll
    for (int s = 0; s < R; ++s) {
        const int b = tid + 256 * s;
        idx_t[c * B + b] = bk[s];

        const float4* dwin = reinterpret_cast<const float4*>(&dict_s[bk[s] * E]);
        const float4 q0 = dwin[0], q1 = dwin[1], q2 = dwin[2], q3 = dwin[3];
        float* zqp = zq + (size_t)b * MUS + (size_t)c * E;
        float* zp  = z  + (size_t)b * MUS + (size_t)c * E;
        reinterpret_cast<float4*>(zqp)[0] = q0;
        reinterpret_cast<float4*>(zqp)[1] = q1;
        reinterpret_cast<float4*>(zqp)[2] = q2;
        reinterpret_cast<float4*>(zqp)[3] = q3;
        float4 z0, z1, z2, z3;
        z0.x = m[s][0].x + (q0.x - m[s][0].x); z0.y = m[s][0].y + (q0.y - m[s][0].y);
        z0.z = m[s][0].z + (q0.z - m[s][0].z); z0.w = m[s][0].w + (q0.w - m[s][0].w);
        z1.x = m[s][1].x + (q1.x - m[s][1].x); z1.y = m[s][1].y + (q1.y - m[s][1].y);
        z1.z = m[s][1].z + (q1.z - m[s][1].z); z1.w = m[s][1].w + (q1.w - m[s][1].w);
        z2.x = m[s][2].x + (q2.x - m[s][2].x); z2.y = m[s][2].y + (q2.y - m[s][2].y);
        z2.z = m[s][2].z + (q2.z - m[s][2].z); z2.w = m[s][2].w + (q2.w - m[s][2].w);
        z3.x = m[s][3].x + (q3.x - m[s][3].x); z3.y = m[s][3].y + (q3.y - m[s][3].y);
        z3.z = m[s][3].z + (q3.z - m[s][3].z); z3.w = m[s][3].w + (q3.w - m[s][3].w);
        reinterpret_cast<float4*>(zp)[0] = z0;
        reinterpret_cast<float4*>(zp)[1] = z1;
        reinterpret_cast<float4*>(zp)[2] = z2;
        reinterpret_cast<float4*>(zp)[3] = z3;
    }
}

// ============================================================================
// Kernel 2 — one-hot writer: perfectly linear grid-stride float4 nt-stores
// over the 512 MB oh buffer (fill-kernel pattern). Row index is wave-uniform
// -> readfirstlane + scalar idx lookup (idx_t is 1 MB, L2-hot).
// (byte-identical to the 669.8us v7 configuration)
// ============================================================================
__launch_bounds__(256)
__global__ void vq_onehot(const int* __restrict__ idx_t,
                          float* __restrict__ oh)
{
    const long TOT = (long)B * C * K / 4;            // 33,554,432 float4s
    const long stride = (long)gridDim.x * blockDim.x;
    long f4 = (long)blockIdx.x * blockDim.x + threadIdx.x;
#pragma unroll 4
    for (; f4 < TOT; f4 += stride) {
        const int rowu = __builtin_amdgcn_readfirstlane((int)(f4 >> 7));
        const int bb   = rowu >> 9;                  // / C
        const int cc   = rowu & (C - 1);
        const int kk   = idx_t[cc * B + bb];         // scalar load, L2-hot
        const int k0   = ((int)f4 & 127) << 2;
        f32x4 v;
        v.x = (k0 + 0 == kk) ? 1.0f : 0.0f;
        v.y = (k0 + 1 == kk) ? 1.0f : 0.0f;
        v.z = (k0 + 2 == kk) ? 1.0f : 0.0f;
        v.w = (k0 + 3 == kk) ? 1.0f : 0.0f;
        __builtin_nontemporal_store(v, reinterpret_cast<f32x4*>(oh) + f4);
    }
}

extern "C" void kernel_launch(void* const* d_in, const int* in_sizes, int n_in,
                              void* d_out, int out_size, void* d_ws, size_t ws_size,
                              hipStream_t stream)
{
    const float* mu   = (const float*)d_in[0];
    const float* dict = (const float*)d_in[1];

    float* z  = (float*)d_out;                 // (B, C*E)
    float* zq = z  + (size_t)B * C * E;        // (B, C*E)
    float* oh = zq + (size_t)B * C * E;        // (B, C, K)

    int* idx_t = (int*)d_ws;                   // C*B*4 = 1 MB workspace

    vq_scan<<<dim3(C), 256, 0, stream>>>(mu, dict, z, zq, idx_t);
    vq_onehot<<<2048, 256, 0, stream>>>(idx_t, oh);
}

// Round 11
// 666.057 us; speedup vs baseline: 1.0266x; 1.0266x over previous
//
#include <hip/hip_runtime.h>
#include <float.h>

// Problem constants (from reference file)
constexpr int C    = 512;          // DIM_CODES
constexpr int K    = 512;          // DICT_SIZE
constexpr int E    = 16;           // EMBED_DIM
constexpr int B    = 512;          // BATCH
constexpr int MUS  = C * E;        // 8192, mu row stride
constexpr int RB   = 256;          // batch rows per block
constexpr int R    = 4;            // rows per lane (64 lanes x 4 = 256)
constexpr int KW   = K / 4;        // k's per wave (4 waves split K)

// native vector type for nontemporal 16B stores
typedef float f32x4 __attribute__((ext_vector_type(4)));

// ============================================================================
// Kernel 1 — argmin scan. v11: K split across waves (iters/wave 512 -> 128).
// Empirical law from v4/v5/v7/v9/v10: scan time = k-iters-per-wave x ~1100cyc,
// INVARIANT to waves/SIMD (1,2,4) and per-iter VALU (R=1,2,4). This kernel
// varies the one axis the law guarantees: wave w scans k in [128w,128w+128)
// for all 256 rows of its block; per-c totals (VALU, LDS instrs) unchanged.
// A 12KB LDS merge then rebuilds EXACTLY the global (bd, sec, bk) per row:
// ascending-wave strict-< merge == first-index ties; equal cross-wave minima
// give sec==bd -> near-tie trigger -> unchanged wave-cooperative fp64 re-scan
// (global-dict variant, verified in v6). All fp32 chains op-for-op identical
// to the verified kernels => bit-identical outputs.
// ============================================================================
__launch_bounds__(256, 2)
__global__ void vq_scan(const float* __restrict__ mu,
                        const float* __restrict__ dict,
                        float* __restrict__ z,
                        float* __restrict__ zq,
                        int*   __restrict__ idx_t)
{
    const int c    = blockIdx.x;
    const int b0   = blockIdx.y * RB;
    const int tid  = threadIdx.x;
    const int lane = tid & 63;
    const int wave = tid >> 6;

    __shared__ __align__(16) float dict_s[K * E];   // 32 KB
    __shared__ float nrm_s[K];                      // 2 KB
    __shared__ float bdm[4][RB];                    // 4 KB  per-wave best
    __shared__ float secm[4][RB];                   // 4 KB  per-wave 2nd-best
    __shared__ int   bkm[4][RB];                    // 4 KB  per-wave argmin

    const float* __restrict__ dbase = dict + (size_t)c * K * E;

    // ---- stage dict slice + per-code squared norms (verified fma order)
#pragma unroll
    for (int rep = 0; rep < 2; ++rep) {
        const int k = tid + rep * 256;
        const float4* p = reinterpret_cast<const float4*>(dbase + k * E);
        const float4 d0 = p[0], d1 = p[1], d2 = p[2], d3 = p[3];
        float s = d0.x * d0.x;
        s = fmaf(d0.y, d0.y, s); s = fmaf(d0.z, d0.z, s); s = fmaf(d0.w, d0.w, s);
        s = fmaf(d1.x, d1.x, s); s = fmaf(d1.y, d1.y, s);
        s = fmaf(d1.z, d1.z, s); s = fmaf(d1.w, d1.w, s);
        s = fmaf(d2.x, d2.x, s); s = fmaf(d2.y, d2.y, s);
        s = fmaf(d2.z, d2.z, s); s = fmaf(d2.w, d2.w, s);
        s = fmaf(d3.x, d3.x, s); s = fmaf(d3.y, d3.y, s);
        s = fmaf(d3.z, d3.z, s); s = fmaf(d3.w, d3.w, s);
        float4* q4 = reinterpret_cast<float4*>(&dict_s[k * E]);
        q4[0] = d0; q4[1] = d1; q4[2] = d2; q4[3] = d3;
        nrm_s[k] = s;
    }
    __syncthreads();

    // ---- this lane's R=4 rows (same rows in every wave): local ell = lane+64s
    float4 m[R][4];
    float  nm[R];
#pragma unroll
    for (int s = 0; s < R; ++s) {
        const int b = b0 + lane + 64 * s;
        const float4* p = reinterpret_cast<const float4*>(
            mu + (size_t)b * MUS + c * E);
        m[s][0] = p[0]; m[s][1] = p[1]; m[s][2] = p[2]; m[s][3] = p[3];
        float v = m[s][0].x * m[s][0].x;
        v = fmaf(m[s][0].y, m[s][0].y, v);
        v = fmaf(m[s][0].z, m[s][0].z, v);
        v = fmaf(m[s][0].w, m[s][0].w, v);
#pragma unroll
        for (int t = 1; t < 4; ++t) {
            v = fmaf(m[s][t].x, m[s][t].x, v);
            v = fmaf(m[s][t].y, m[s][t].y, v);
            v = fmaf(m[s][t].z, m[s][t].z, v);
            v = fmaf(m[s][t].w, m[s][t].w, v);
        }
        nm[s] = v;
    }

    // ---- scan THIS WAVE's k-range only: k in [kbase, kbase+KW)
    float bd[R], sec[R];
    int   bk[R];
#pragma unroll
    for (int s = 0; s < R; ++s) { bd[s] = FLT_MAX; sec[s] = FLT_MAX; bk[s] = K; }

    const float4* __restrict__ ds4 = reinterpret_cast<const float4*>(dict_s);
    const int kbase = wave * KW;
#pragma unroll 4
    for (int i = 0; i < KW; ++i) {
        const int k = kbase + i;
        const float4 d0 = ds4[k * 4 + 0];
        const float4 d1 = ds4[k * 4 + 1];
        const float4 d2 = ds4[k * 4 + 2];
        const float4 d3 = ds4[k * 4 + 3];
        const float  nr = nrm_s[k];
#pragma unroll
        for (int s = 0; s < R; ++s) {
            float acc = d0.x * m[s][0].x;
            acc = fmaf(d0.y, m[s][0].y, acc);
            acc = fmaf(d0.z, m[s][0].z, acc);
            acc = fmaf(d0.w, m[s][0].w, acc);
            acc = fmaf(d1.x, m[s][1].x, acc);
            acc = fmaf(d1.y, m[s][1].y, acc);
            acc = fmaf(d1.z, m[s][1].z, acc);
            acc = fmaf(d1.w, m[s][1].w, acc);
            acc = fmaf(d2.x, m[s][2].x, acc);
            acc = fmaf(d2.y, m[s][2].y, acc);
            acc = fmaf(d2.z, m[s][2].z, acc);
            acc = fmaf(d2.w, m[s][2].w, acc);
            acc = fmaf(d3.x, m[s][3].x, acc);
            acc = fmaf(d3.y, m[s][3].y, acc);
            acc = fmaf(d3.z, m[s][3].z, acc);
            acc = fmaf(d3.w, m[s][3].w, acc);
            // identical rounding to the verified kernel
            const float dist = fmaf(-2.0f, acc, nm[s] + nr);
            const bool  lt   = dist < bd[s];          // ascending k =>
            sec[s] = lt ? bd[s] : fminf(sec[s], dist);   // first-index ties
            bd[s]  = lt ? dist : bd[s];
            bk[s]  = lt ? k : bk[s];
        }
    }

    // ---- publish per-wave results (stride-1 across lanes per s)
#pragma unroll
    for (int s = 0; s < R; ++s) {
        const int ell = lane + 64 * s;
        bdm[wave][ell]  = bd[s];
        secm[wave][ell] = sec[s];
        bkm[wave][ell]  = bk[s];
    }
    __syncthreads();

    // ---- merge (thread tid owns local row ell = tid): exact global
    // (best, second-best, first-index argmin) reconstruction.
    float gbd = bdm[0][tid], gsec = secm[0][tid];
    int   gbk = bkm[0][tid];
#pragma unroll
    for (int w = 1; w < 4; ++w) {
        const float bw = bdm[w][tid];
        const float sw = secm[w][tid];
        const int   kw = bkm[w][tid];
        if (bw < gbd) { gsec = fminf(gbd, sw); gbd = bw; gbk = kw; }
        else          { gsec = fminf(gsec, bw); }
    }

    // ---- rare near-tie path: wave-cooperative fp64 re-scan per flagged row
    // (global-dict variant, verified in v6; identical fp64 ops).
    {
        unsigned long long trig = __ballot(gsec < gbd + 1e-3f);
        while (trig) {
            const int r = __ffsll(trig) - 1;
            trig &= trig - 1;
            const int row = b0 + (wave << 6) + r;
            const float* __restrict__ qrow = mu + (size_t)row * MUS + c * E;

            double nmuD = 0.0;
#pragma unroll
            for (int t = 0; t < E; ++t) {
                const double mt = (double)qrow[t];
                nmuD += mt * mt;
            }
            double bD = DBL_MAX;
            int    bK = K;
#pragma unroll
            for (int i = 0; i < 8; ++i) {
                const int kk = lane + 64 * i;
                const float* dk = dbase + (size_t)kk * E;   // L2-hot global
                double nd = 0.0, dt = 0.0;
#pragma unroll
                for (int t = 0; t < 4; ++t) {
                    const double dx = dk[4 * t + 0], dy = dk[4 * t + 1];
                    const double dz = dk[4 * t + 2], dw = dk[4 * t + 3];
                    const double mx = qrow[4 * t + 0], my = qrow[4 * t + 1];
                    const double mz = qrow[4 * t + 2], mw = qrow[4 * t + 3];
                    nd += dx * dx + dy * dy + dz * dz + dw * dw;
                    dt += dx * mx + dy * my + dz * mz + dw * mw;
                }
                const double dist = nmuD + nd - 2.0 * dt;
                if (dist < bD) { bD = dist; bK = kk; }
            }
#pragma unroll
            for (int off = 32; off; off >>= 1) {
                const double od = __shfl_down(bD, off);
                const int    ok = __shfl_down(bK, off);
                if (od < bD || (od == bD && ok < bK)) { bD = od; bK = ok; }
            }
            const int kwin = __shfl(bK, 0);
            if (lane == r) gbk = kwin;
        }
    }

    // ---- outputs (thread tid owns row b0+tid): idx, z/zq.
    {
        const int b = b0 + tid;
        idx_t[c * B + b] = gbk;

        const float4* mp = reinterpret_cast<const float4*>(
            mu + (size_t)b * MUS + c * E);                   // L1/L2-hot reload
        const float4 mm0 = mp[0], mm1 = mp[1], mm2 = mp[2], mm3 = mp[3];
        const float4* dwin = reinterpret_cast<const float4*>(&dict_s[gbk * E]);
        const float4 q0 = dwin[0], q1 = dwin[1], q2 = dwin[2], q3 = dwin[3];

        float* zqp = zq + (size_t)b * MUS + (size_t)c * E;
        float* zp  = z  + (size_t)b * MUS + (size_t)c * E;
        reinterpret_cast<float4*>(zqp)[0] = q0;
        reinterpret_cast<float4*>(zqp)[1] = q1;
        reinterpret_cast<float4*>(zqp)[2] = q2;
        reinterpret_cast<float4*>(zqp)[3] = q3;
        float4 z0, z1, z2, z3;
        z0.x = mm0.x + (q0.x - mm0.x); z0.y = mm0.y + (q0.y - mm0.y);
        z0.z = mm0.z + (q0.z - mm0.z); z0.w = mm0.w + (q0.w - mm0.w);
        z1.x = mm1.x + (q1.x - mm1.x); z1.y = mm1.y + (q1.y - mm1.y);
        z1.z = mm1.z + (q1.z - mm1.z); z1.w = mm1.w + (q1.w - mm1.w);
        z2.x = mm2.x + (q2.x - mm2.x); z2.y = mm2.y + (q2.y - mm2.y);
        z2.z = mm2.z + (q2.z - mm2.z); z2.w = mm2.w + (q2.w - mm2.w);
        z3.x = mm3.x + (q3.x - mm3.x); z3.y = mm3.y + (q3.y - mm3.y);
        z3.z = mm3.z + (q3.z - mm3.z); z3.w = mm3.w + (q3.w - mm3.w);
        reinterpret_cast<float4*>(zp)[0] = z0;
        reinterpret_cast<float4*>(zp)[1] = z1;
        reinterpret_cast<float4*>(zp)[2] = z2;
        reinterpret_cast<float4*>(zp)[3] = z3;
    }
}

// ============================================================================
// Kernel 2 — one-hot writer: perfectly linear grid-stride float4 nt-stores
// over the 512 MB oh buffer (fill-kernel pattern). Row index is wave-uniform
// -> readfirstlane + scalar idx lookup (idx_t is 1 MB, L2-hot).
// (byte-identical to the 669.8us v7 configuration)
// ============================================================================
__launch_bounds__(256)
__global__ void vq_onehot(const int* __restrict__ idx_t,
                          float* __restrict__ oh)
{
    const long TOT = (long)B * C * K / 4;            // 33,554,432 float4s
    const long stride = (long)gridDim.x * blockDim.x;
    long f4 = (long)blockIdx.x * blockDim.x + threadIdx.x;
#pragma unroll 4
    for (; f4 < TOT; f4 += stride) {
        const int rowu = __builtin_amdgcn_readfirstlane((int)(f4 >> 7));
        const int bb   = rowu >> 9;                  // / C
        const int cc   = rowu & (C - 1);
        const int kk   = idx_t[cc * B + bb];         // scalar load, L2-hot
        const int k0   = ((int)f4 & 127) << 2;
        f32x4 v;
        v.x = (k0 + 0 == kk) ? 1.0f : 0.0f;
        v.y = (k0 + 1 == kk) ? 1.0f : 0.0f;
        v.z = (k0 + 2 == kk) ? 1.0f : 0.0f;
        v.w = (k0 + 3 == kk) ? 1.0f : 0.0f;
        __builtin_nontemporal_store(v, reinterpret_cast<f32x4*>(oh) + f4);
    }
}

extern "C" void kernel_launch(void* const* d_in, const int* in_sizes, int n_in,
                              void* d_out, int out_size, void* d_ws, size_t ws_size,
                              hipStream_t stream)
{
    const float* mu   = (const float*)d_in[0];
    const float* dict = (const float*)d_in[1];

    float* z  = (float*)d_out;                 // (B, C*E)
    float* zq = z  + (size_t)B * C * E;        // (B, C*E)
    float* oh = zq + (size_t)B * C * E;        // (B, C, K)

    int* idx_t = (int*)d_ws;                   // C*B*4 = 1 MB workspace

    vq_scan<<<dim3(C, B / RB), 256, 0, stream>>>(mu, dict, z, zq, idx_t);
    vq_onehot<<<2048, 256, 0, stream>>>(idx_t, oh);
}

// Round 12
// 647.312 us; speedup vs baseline: 1.0564x; 1.0290x over previous
//
#include <hip/hip_runtime.h>
#include <float.h>

// Problem constants (from reference file)
constexpr int C    = 512;          // DIM_CODES
constexpr int K    = 512;          // DICT_SIZE
constexpr int E    = 16;           // EMBED_DIM
constexpr int B    = 512;          // BATCH
constexpr int MUS  = C * E;        // 8192, mu row stride

// near-tie trigger: 1e-3 (verified) + 2*eps_mfma (~8e-4) + 2*eps_ref (~2e-4)
#define TAU 2.5e-3f

typedef float f32x4  __attribute__((ext_vector_type(4)));
typedef __attribute__((ext_vector_type(8)))  short short8;
typedef __attribute__((ext_vector_type(16))) float f32x16;

__device__ __forceinline__ unsigned short bf16_rne(float f) {
    unsigned u = __float_as_uint(f);
    u += 0x7FFFu + ((u >> 16) & 1u);
    return (unsigned short)(u >> 16);
}
__device__ __forceinline__ float bf16_f32(unsigned short h) {
    return __uint_as_float(((unsigned)h) << 16);
}

// ============================================================================
// Kernel 1 — MFMA argmin screen. 12 rounds showed the VALU screen of the
// 134M (b,c,k) distances is stuck at ~200-255us (~5x VALU-issue floor,
// invariant to every scheduling structure). Replace it with matrix math:
// per c (one block), S[k,b] = nrm[k] + mfma4(-2*dict_bf16split, mu_bf16split)
// using 32x32x16 bf16 MFMA (E=16 == MFMA K). 4-pass hi/lo split bounds
// |screen - exact| <= ~8e-4 for N(0,1) data; trigger tau=2.5e-3 guarantees
// any row where the screen could disagree with the verified fp32 screen goes
// to the UNCHANGED wave-cooperative fp64 re-scan => outputs identical to the
// verified kernels. nm[b] dropped (constant over k; gap is nm-invariant).
// C/D layout (HW-verified): col=lane&31, row=(reg&3)+8*(reg>>2)+4*(lane>>5).
// A: lane=row(l&31), e=(l>>5)*8+j.  B: lane=col(l&31), e=(l>>5)*8+j.
// ============================================================================
__launch_bounds__(256, 2)
__global__ void vq_scan(const float* __restrict__ mu,
                        const float* __restrict__ dict,
                        float* __restrict__ z,
                        float* __restrict__ zq,
                        int*   __restrict__ idx_t)
{
    const int c    = blockIdx.x;
    const int tid  = threadIdx.x;
    const int lane = tid & 63;
    const int wave = tid >> 6;
    const int lr   = lane & 31;
    const int lh   = lane >> 5;         // lane half (e-block for A/B frags)

    __shared__ __align__(16) unsigned short Ahi[16][64][8];   // 16 KB
    __shared__ __align__(16) unsigned short Alo[16][64][8];   // 16 KB
    __shared__ float nrm_s[K];                                 // 2 KB

    const float* __restrict__ dbase = dict + (size_t)c * K * E;

    // ---- stage dict: nrm (verified fma chain on ORIGINAL values) + bf16
    // hi/lo split of (-2*dict) into A-fragment layout.
#pragma unroll
    for (int rep = 0; rep < 2; ++rep) {
        const int k = tid + rep * 256;
        const float4* p = reinterpret_cast<const float4*>(dbase + k * E);
        const float4 d0 = p[0], d1 = p[1], d2 = p[2], d3 = p[3];
        float s = d0.x * d0.x;
        s = fmaf(d0.y, d0.y, s); s = fmaf(d0.z, d0.z, s); s = fmaf(d0.w, d0.w, s);
        s = fmaf(d1.x, d1.x, s); s = fmaf(d1.y, d1.y, s);
        s = fmaf(d1.z, d1.z, s); s = fmaf(d1.w, d1.w, s);
        s = fmaf(d2.x, d2.x, s); s = fmaf(d2.y, d2.y, s);
        s = fmaf(d2.z, d2.z, s); s = fmaf(d2.w, d2.w, s);
        s = fmaf(d3.x, d3.x, s); s = fmaf(d3.y, d3.y, s);
        s = fmaf(d3.z, d3.z, s); s = fmaf(d3.w, d3.w, s);
        nrm_s[k] = s;

        const float de[16] = { d0.x, d0.y, d0.z, d0.w, d1.x, d1.y, d1.z, d1.w,
                               d2.x, d2.y, d2.z, d2.w, d3.x, d3.y, d3.z, d3.w };
        const int kt = k >> 5, kr = k & 31;
#pragma unroll
        for (int j = 0; j < 8; ++j) {
            // e = j  -> frag row kr (half 0);  e = 8+j -> frag row 32+kr
            float f0 = -2.0f * de[j];
            unsigned short h0 = bf16_rne(f0);
            Ahi[kt][kr][j] = h0;
            Alo[kt][kr][j] = bf16_rne(f0 - bf16_f32(h0));
            float f1 = -2.0f * de[8 + j];
            unsigned short h1 = bf16_rne(f1);
            Ahi[kt][32 + kr][j] = h1;
            Alo[kt][32 + kr][j] = bf16_rne(f1 - bf16_f32(h1));
        }
    }
    __syncthreads();

    // ---- B fragments (mu) straight from global into registers:
    // wave owns b-tiles bt = 4*wave + j; lane lr = col, lh*8+j = e.
    short8 bh[4], bl[4];
#pragma unroll
    for (int j = 0; j < 4; ++j) {
        const int bt = wave * 4 + j;
        const int b  = bt * 32 + lr;
        const float4* mp = reinterpret_cast<const float4*>(
            mu + (size_t)b * MUS + c * E + lh * 8);
        const float4 x0 = mp[0], x1 = mp[1];
        const float me[8] = { x0.x, x0.y, x0.z, x0.w, x1.x, x1.y, x1.z, x1.w };
        unsigned short hh[8], ll[8];
#pragma unroll
        for (int e = 0; e < 8; ++e) {
            hh[e] = bf16_rne(me[e]);
            ll[e] = bf16_rne(me[e] - bf16_f32(hh[e]));
        }
        bh[j] = *reinterpret_cast<const short8*>(hh);
        bl[j] = *reinterpret_cast<const short8*>(ll);
    }

    // ---- screen: 16 k-tiles x 4 b-tiles x 4 MFMA passes; per-lane argmin.
    float bd[4], sec[4];
    int   bk[4];
#pragma unroll
    for (int j = 0; j < 4; ++j) { bd[j] = FLT_MAX; sec[j] = FLT_MAX; bk[j] = K; }

    for (int kt = 0; kt < 16; ++kt) {
        const short8 ah = *reinterpret_cast<const short8*>(&Ahi[kt][lane][0]);
        const short8 al = *reinterpret_cast<const short8*>(&Alo[kt][lane][0]);
        float nr[16];
#pragma unroll
        for (int r = 0; r < 16; ++r)
            nr[r] = nrm_s[kt * 32 + (r & 3) + 8 * (r >> 2) + 4 * lh];

#pragma unroll
        for (int j = 0; j < 4; ++j) {
            f32x16 acc = {};
            acc = __builtin_amdgcn_mfma_f32_32x32x16_bf16(ah, bh[j], acc, 0, 0, 0);
            acc = __builtin_amdgcn_mfma_f32_32x32x16_bf16(ah, bl[j], acc, 0, 0, 0);
            acc = __builtin_amdgcn_mfma_f32_32x32x16_bf16(al, bh[j], acc, 0, 0, 0);
            acc = __builtin_amdgcn_mfma_f32_32x32x16_bf16(al, bl[j], acc, 0, 0, 0);
#pragma unroll
            for (int r = 0; r < 16; ++r) {
                const float S = acc[r] + nr[r];
                const int   k = kt * 32 + (r & 3) + 8 * (r >> 2) + 4 * lh;
                const bool  lt = S < bd[j];            // rows ascend per lane
                sec[j] = lt ? bd[j] : fminf(sec[j], S);   // => first-index ties
                bd[j]  = lt ? S : bd[j];
                bk[j]  = lt ? k : bk[j];
            }
        }
    }

    // ---- merge the two lane-halves of each b-column (exact, index tiebreak;
    // exact value ties trigger fp64 anyway since gap==0 < TAU).
#pragma unroll
    for (int j = 0; j < 4; ++j) {
        const float od = __shfl_xor(bd[j], 32);
        const float os = __shfl_xor(sec[j], 32);
        const int   ok = __shfl_xor(bk[j], 32);
        if (od < bd[j] || (od == bd[j] && ok < bk[j])) {
            sec[j] = fminf(bd[j], os); bd[j] = od; bk[j] = ok;
        } else {
            sec[j] = fminf(sec[j], od);
        }
    }

    // ---- per b-tile: near-tie fp64 re-scan (UNCHANGED verified path) + outputs
#pragma unroll
    for (int j = 0; j < 4; ++j) {
        const int bt = wave * 4 + j;

        unsigned long long trig = __ballot(lane < 32 && (sec[j] - bd[j] < TAU));
        while (trig) {
            const int r = __ffsll(trig) - 1;
            trig &= trig - 1;
            const int row = bt * 32 + r;
            const float* __restrict__ qrow = mu + (size_t)row * MUS + c * E;

            double nmuD = 0.0;
#pragma unroll
            for (int t = 0; t < E; ++t) {
                const double mt = (double)qrow[t];
                nmuD += mt * mt;
            }
            double bD = DBL_MAX;
            int    bK = K;
#pragma unroll
            for (int i = 0; i < 8; ++i) {
                const int kk = lane + 64 * i;
                const float* dk = dbase + (size_t)kk * E;   // L2-hot global
                double nd = 0.0, dt = 0.0;
#pragma unroll
                for (int t = 0; t < 4; ++t) {
                    const double dx = dk[4 * t + 0], dy = dk[4 * t + 1];
                    const double dz = dk[4 * t + 2], dw = dk[4 * t + 3];
                    const double mx = qrow[4 * t + 0], my = qrow[4 * t + 1];
                    const double mz = qrow[4 * t + 2], mw = qrow[4 * t + 3];
                    nd += dx * dx + dy * dy + dz * dz + dw * dw;
                    dt += dx * mx + dy * my + dz * mz + dw * mw;
                }
                const double dist = nmuD + nd - 2.0 * dt;
                if (dist < bD) { bD = dist; bK = kk; }
            }
#pragma unroll
            for (int off = 32; off; off >>= 1) {
                const double od = __shfl_down(bD, off);
                const int    ok = __shfl_down(bK, off);
                if (od < bD || (od == bD && ok < bK)) { bD = od; bK = ok; }
            }
            const int kwin = __shfl(bK, 0);
            if (lane == r) bk[j] = kwin;
        }

        if (lane < 32) {
            const int b = bt * 32 + lane;
            idx_t[c * B + b] = bk[j];

            const float4* mp = reinterpret_cast<const float4*>(
                mu + (size_t)b * MUS + c * E);               // L2-hot reload
            const float4 m0 = mp[0], m1 = mp[1], m2 = mp[2], m3 = mp[3];
            const float4* dwin = reinterpret_cast<const float4*>(
                dbase + (size_t)bk[j] * E);                  // L2-hot
            const float4 q0 = dwin[0], q1 = dwin[1], q2 = dwin[2], q3 = dwin[3];

            float* zqp = zq + (size_t)b * MUS + (size_t)c * E;
            float* zp  = z  + (size_t)b * MUS + (size_t)c * E;
            reinterpret_cast<float4*>(zqp)[0] = q0;
            reinterpret_cast<float4*>(zqp)[1] = q1;
            reinterpret_cast<float4*>(zqp)[2] = q2;
            reinterpret_cast<float4*>(zqp)[3] = q3;
            float4 z0, z1, z2, z3;
            z0.x = m0.x + (q0.x - m0.x); z0.y = m0.y + (q0.y - m0.y);
            z0.z = m0.z + (q0.z - m0.z); z0.w = m0.w + (q0.w - m0.w);
            z1.x = m1.x + (q1.x - m1.x); z1.y = m1.y + (q1.y - m1.y);
            z1.z = m1.z + (q1.z - m1.z); z1.w = m1.w + (q1.w - m1.w);
            z2.x = m2.x + (q2.x - m2.x); z2.y = m2.y + (q2.y - m2.y);
            z2.z = m2.z + (q2.z - m2.z); z2.w = m2.w + (q2.w - m2.w);
            z3.x = m3.x + (q3.x - m3.x); z3.y = m3.y + (q3.y - m3.y);
            z3.z = m3.z + (q3.z - m3.z); z3.w = m3.w + (q3.w - m3.w);
            reinterpret_cast<float4*>(zp)[0] = z0;
            reinterpret_cast<float4*>(zp)[1] = z1;
            reinterpret_cast<float4*>(zp)[2] = z2;
            reinterpret_cast<float4*>(zp)[3] = z3;
        }
    }
}

// ============================================================================
// Kernel 2 — one-hot writer (byte-identical to the 669.8us v7 configuration).
// ============================================================================
__launch_bounds__(256)
__global__ void vq_onehot(const int* __restrict__ idx_t,
                          float* __restrict__ oh)
{
    const long TOT = (long)B * C * K / 4;            // 33,554,432 float4s
    const long stride = (long)gridDim.x * blockDim.x;
    long f4 = (long)blockIdx.x * blockDim.x + threadIdx.x;
#pragma unroll 4
    for (; f4 < TOT; f4 += stride) {
        const int rowu = __builtin_amdgcn_readfirstlane((int)(f4 >> 7));
        const int bb   = rowu >> 9;                  // / C
        const int cc   = rowu & (C - 1);
        const int kk   = idx_t[cc * B + bb];         // scalar load, L2-hot
        const int k0   = ((int)f4 & 127) << 2;
        f32x4 v;
        v.x = (k0 + 0 == kk) ? 1.0f : 0.0f;
        v.y = (k0 + 1 == kk) ? 1.0f : 0.0f;
        v.z = (k0 + 2 == kk) ? 1.0f : 0.0f;
        v.w = (k0 + 3 == kk) ? 1.0f : 0.0f;
        __builtin_nontemporal_store(v, reinterpret_cast<f32x4*>(oh) + f4);
    }
}

extern "C" void kernel_launch(void* const* d_in, const int* in_sizes, int n_in,
                              void* d_out, int out_size, void* d_ws, size_t ws_size,
                              hipStream_t stream)
{
    const float* mu   = (const float*)d_in[0];
    const float* dict = (const float*)d_in[1];

    float* z  = (float*)d_out;                 // (B, C*E)
    float* zq = z  + (size_t)B * C * E;        // (B, C*E)
    float* oh = zq + (size_t)B * C * E;        // (B, C, K)

    int* idx_t = (int*)d_ws;                   // C*B*4 = 1 MB workspace

    vq_scan<<<dim3(C), 256, 0, stream>>>(mu, dict, z, zq, idx_t);
    vq_onehot<<<2048, 256, 0, stream>>>(idx_t, oh);
}